// Round 1
// baseline (1050.504 us; speedup 1.0000x reference)
//
#include <hip/hip_runtime.h>
#include <math.h>

#define NSAMP 446
#define STILE 32
#define ACT_SHIFT -4.5951198501345889f

// Generic LDS-resident dense stage: out[s][j] = act(sum_i in[s][i]*W[i][j] + b[j])
// 256 threads; thread owns column jt = t % DOUT, samples sg*NS..sg*NS+NS-1.
template<int DIN, int DOUT, bool RELU, bool BIAS>
__device__ __forceinline__ void stage(const float* in_lds, float* out_lds,
                                      const float* __restrict__ W,
                                      const float* __restrict__ b, int t) {
  constexpr int NSG = 256 / DOUT;
  constexpr int NS  = STILE / NSG;
  const int jt = t % DOUT;
  const int sg = t / DOUT;
  float acc[NS];
#pragma unroll
  for (int k = 0; k < NS; ++k) acc[k] = BIAS ? b[jt] : 0.0f;
#pragma unroll 2
  for (int i = 0; i < DIN; ++i) {
    float w = W[i * DOUT + jt];
#pragma unroll
    for (int k = 0; k < NS; ++k)
      acc[k] = fmaf(in_lds[(sg * NS + k) * DIN + i], w, acc[k]);
  }
#pragma unroll
  for (int k = 0; k < NS; ++k) {
    float v = acc[k];
    if (RELU) v = fmaxf(v, 0.0f);
    out_lds[(sg * NS + k) * DOUT + jt] = v;
  }
}

extern "C" __global__ void __launch_bounds__(256)
ssg_render(const float* __restrict__ rays_o, const float* __restrict__ rays_d,
           const float* __restrict__ viewdirs, const float* __restrict__ grid,
           const float* __restrict__ fv,
           const float* __restrict__ mW1, const float* __restrict__ mb1,
           const float* __restrict__ mW2, const float* __restrict__ mb2,
           const float* __restrict__ mW3, const float* __restrict__ mb3,
           const float* __restrict__ pW1, const float* __restrict__ pb1,
           const float* __restrict__ pW2, const float* __restrict__ pb2,
           const float* __restrict__ pW3, const float* __restrict__ pb3,
           const float* __restrict__ dW1, const float* __restrict__ db1,
           const float* __restrict__ dW2, const float* __restrict__ db2,
           const float* __restrict__ dW3, const float* __restrict__ db3,
           const float* __restrict__ dW4, const float* __restrict__ db4,
           float* __restrict__ out) {
  const int r = blockIdx.x;
  const int t = threadIdx.x;

  __shared__ float A[STILE * 128];
  __shared__ float B[STILE * 128];
  __shared__ float ptl[STILE][3];
  __shared__ int   validl[STILE];
  __shared__ float alph[STILE];
  __shared__ float rgbl[STILE][3];
  __shared__ float emb[40];
  __shared__ int   anyvalid;

  // ---- per-ray setup (redundant across threads; cheap) ----
  const float ox = rays_o[r*3+0], oy = rays_o[r*3+1], oz = rays_o[r*3+2];
  const float dx = rays_d[r*3+0], dy = rays_d[r*3+1], dz = rays_d[r*3+2];
  const float vx = (dx == 0.0f) ? 1e-6f : dx;
  const float vy = (dy == 0.0f) ? 1e-6f : dy;
  const float vz = (dz == 0.0f) ? 1e-6f : dz;
  const float rax = ( 1.0f - ox) / vx, rbx = (-1.0f - ox) / vx;
  const float ray_ = ( 1.0f - oy) / vy, rby = (-1.0f - oy) / vy;
  const float raz = ( 1.0f - oz) / vz, rbz = (-1.0f - oz) / vz;
  float tmin = fmaxf(fmaxf(fminf(rax,rbx), fminf(ray_,rby)), fminf(raz,rbz));
  tmin = fminf(fmaxf(tmin, 0.2f), 3.0f);
  float tmax = fminf(fminf(fmaxf(rax,rbx), fmaxf(ray_,rby)), fmaxf(raz,rbz));
  tmax = fminf(fmaxf(tmax, 0.2f), 3.0f);

  if (tmax <= tmin) {            // ray misses box: rgb_marched = BG = 1
    if (t < 3) out[r*3+t] = 1.0f;
    return;
  }
  const float nrm = sqrtf(dx*dx + dy*dy + dz*dz);

  // directional embedding: [v, sin(v*2^f), cos(v*2^f)] f-major, 39 dims
  if (t < 39) {
    const float v0 = viewdirs[r*3+0], v1 = viewdirs[r*3+1], v2 = viewdirs[r*3+2];
    float val;
    if (t < 3) {
      val = (t==0) ? v0 : ((t==1) ? v1 : v2);
    } else {
      int q = t - 3, fr = q / 6, rm = q % 6;
      float f = (float)(1 << fr);
      int c = rm % 3;
      float comp = (c==0) ? v0 : ((c==1) ? v1 : v2);
      float ang = comp * f;
      val = (rm < 3) ? sinf(ang) : cosf(ang);
    }
    emb[t] = val;
  }

  float T = 1.0f, accr = 0.0f, accg = 0.0f, accb = 0.0f;  // live in t==0

  for (int s0 = 0; s0 < NSAMP; s0 += STILE) {
    if (t == 0) anyvalid = 0;
    __syncthreads();

    int myvalid = 0;
    if (t < STILE) {
      int s = s0 + t;
      float px = 0.f, py = 0.f, pz = 0.f;
      if (s < NSAMP) {
        float ix = tmin + (0.0078125f * (float)s) / nrm;  // STEPSIZE*VOXEL*s/|d|
        px = ox + dx * ix;
        py = oy + dy * ix;
        pz = oz + dz * ix;
        myvalid = !(px < -1.f || px > 1.f || py < -1.f || py > 1.f ||
                    pz < -1.f || pz > 1.f);
      }
      ptl[t][0] = px; ptl[t][1] = py; ptl[t][2] = pz;
      validl[t] = myvalid;
      if (myvalid) anyvalid = 1;
    }
    __syncthreads();

    if (anyvalid) {
      // ---- trilinear interp: thread (s = t&31, c = t>>5), 4 channels ----
      if (t < 128) {
        int s = t & 31, c = t >> 5;
        float mpv = 0.0f;
        if (validl[s]) {
          float px = ptl[s][0], py = ptl[s][1], pz = ptl[s][2];
          float ixf = fminf(fmaxf((px + 1.0f) * 0.5f * 255.0f, 0.0f), 255.0f);
          float iyf = fminf(fmaxf((py + 1.0f) * 0.5f * 255.0f, 0.0f), 255.0f);
          float izf = fminf(fmaxf((pz + 1.0f) * 0.5f * 255.0f, 0.0f), 255.0f);
          int x0 = min((int)ixf, 254), y0 = min((int)iyf, 254), z0 = min((int)izf, 254);
          float fx = ixf - (float)x0, fy = iyf - (float)y0, fz = izf - (float)z0;
          const float* gc = grid + (size_t)c * 16777216u;
          int bx0 = x0 << 16, bx1 = bx0 + 65536;
          int by0 = y0 << 8,  by1 = by0 + 256;
          float c000 = gc[bx0+by0+z0], c001 = gc[bx0+by0+z0+1];
          float c010 = gc[bx0+by1+z0], c011 = gc[bx0+by1+z0+1];
          float c100 = gc[bx1+by0+z0], c101 = gc[bx1+by0+z0+1];
          float c110 = gc[bx1+by1+z0], c111 = gc[bx1+by1+z0+1];
          float c00 = c000*(1.f-fz) + c001*fz;
          float c01 = c010*(1.f-fz) + c011*fz;
          float c10 = c100*(1.f-fz) + c101*fz;
          float c11 = c110*(1.f-fz) + c111*fz;
          float c0 = c00*(1.f-fy) + c01*fy;
          float c1 = c10*(1.f-fy) + c11*fy;
          mpv = c0*(1.f-fx) + c1*fx;
        }
        A[s*4 + c] = mpv;
      }
      __syncthreads();

      stage<4,128,true,true>(A, B, mW1, mb1, t);   __syncthreads();
      stage<128,128,true,true>(B, A, mW2, mb2, t); __syncthreads();
      stage<128,32,false,true>(A, B, mW3, mb3, t); __syncthreads();

      // softmax over 32 logits, one thread per sample
      if (t < STILE) {
        float m = -1e30f;
        for (int i = 0; i < 32; ++i) m = fmaxf(m, B[t*32+i]);
        float sum = 0.0f;
        for (int i = 0; i < 32; ++i) { float e = expf(B[t*32+i] - m); B[t*32+i] = e; sum += e; }
        float inv = 1.0f / sum;
        for (int i = 0; i < 32; ++i) B[t*32+i] *= inv;
      }
      __syncthreads();

      stage<32,64,false,false>(B, A, fv, nullptr, t); __syncthreads();
      stage<64,64,true,true>(A, B, pW1, pb1, t);      __syncthreads();
      stage<64,64,true,true>(B, A, pW2, pb2, t);      __syncthreads();
      stage<64,16,false,true>(A, B, pW3, pb3, t);     __syncthreads();

      // alpha from pos[...,0]; build rgb_feat = [rgb_latent(15), emb(39)] in A
      if (t < STILE) {
        float a = 0.0f;
        if (validl[t]) {
          float x = B[t*16] + ACT_SHIFT;
          float sp = fmaxf(x, 0.0f) + log1pf(expf(-fabsf(x)));  // stable softplus
          a = 1.0f - expf(-sp);
        }
        alph[t] = a;
      }
      for (int idx = t; idx < STILE*54; idx += 256) {
        int s = idx / 54, j = idx % 54;
        float val = (j < 15) ? (validl[s] ? B[s*16 + 1 + j] : 0.0f) : emb[j - 15];
        A[s*54 + j] = val;
      }
      __syncthreads();

      stage<54,64,true,true>(A, B, dW1, db1, t); __syncthreads();
      stage<64,64,true,true>(B, A, dW2, db2, t); __syncthreads();
      stage<64,64,true,true>(A, B, dW3, db3, t); __syncthreads();

      if (t < 96) {   // raw_rgb (dout=3) + sigmoid
        int s = t / 3, c = t % 3;
        float acc = db4[c];
        for (int i = 0; i < 64; ++i) acc = fmaf(B[s*64+i], dW4[i*3+c], acc);
        rgbl[s][c] = validl[s] ? (1.0f / (1.0f + expf(-acc))) : 0.0f;
      }
      __syncthreads();

      // sequential transmittance scan for this tile (order matters)
      if (t == 0) {
        int smax = min(STILE, NSAMP - s0);
        for (int k = 0; k < smax; ++k) {
          float a = alph[k];
          float w = a * T;
          accr = fmaf(w, rgbl[k][0], accr);
          accg = fmaf(w, rgbl[k][1], accg);
          accb = fmaf(w, rgbl[k][2], accb);
          T *= fmaxf(1.0f - a, 1e-10f);
        }
      }
    }
    __syncthreads();
  }

  if (t == 0) {
    out[r*3+0] = accr + T;   // + alphainv_cum[-1] * BG, BG = 1
    out[r*3+1] = accg + T;
    out[r*3+2] = accb + T;
  }
}

extern "C" void kernel_launch(void* const* d_in, const int* in_sizes, int n_in,
                              void* d_out, int out_size, void* d_ws, size_t ws_size,
                              hipStream_t stream) {
  const float* rays_o   = (const float*)d_in[0];
  const float* rays_d   = (const float*)d_in[1];
  const float* viewdirs = (const float*)d_in[2];
  const float* grid     = (const float*)d_in[3];
  const float* fv       = (const float*)d_in[4];
  const float* mW1 = (const float*)d_in[5];  const float* mb1 = (const float*)d_in[6];
  const float* mW2 = (const float*)d_in[7];  const float* mb2 = (const float*)d_in[8];
  const float* mW3 = (const float*)d_in[9];  const float* mb3 = (const float*)d_in[10];
  const float* pW1 = (const float*)d_in[11]; const float* pb1 = (const float*)d_in[12];
  const float* pW2 = (const float*)d_in[13]; const float* pb2 = (const float*)d_in[14];
  const float* pW3 = (const float*)d_in[15]; const float* pb3 = (const float*)d_in[16];
  const float* dW1 = (const float*)d_in[17]; const float* db1 = (const float*)d_in[18];
  const float* dW2 = (const float*)d_in[19]; const float* db2 = (const float*)d_in[20];
  const float* dW3 = (const float*)d_in[21]; const float* db3 = (const float*)d_in[22];
  const float* dW4 = (const float*)d_in[23]; const float* db4 = (const float*)d_in[24];
  float* out = (float*)d_out;

  const int n_rays = in_sizes[0] / 3;
  ssg_render<<<n_rays, 256, 0, stream>>>(
      rays_o, rays_d, viewdirs, grid, fv,
      mW1, mb1, mW2, mb2, mW3, mb3,
      pW1, pb1, pW2, pb2, pW3, pb3,
      dW1, db1, dW2, db2, dW3, db3, dW4, db4,
      out);
}

// Round 2
// 469.172 us; speedup vs baseline: 2.2391x; 2.2391x over previous
//
#include <hip/hip_runtime.h>
#include <math.h>

#define NSAMP 446
#define STILE 32
#define NCHUNK 14            // ceil(446/32)
#define NSPAD  (NCHUNK * 32) // 448
#define ACT_SHIFT -4.5951198501345889f

struct Wt {
  const float *mW1,*mb1,*mW2,*mb2,*mW3,*mb3,*fv;
  const float *pW1,*pb1,*pW2,*pb2,*pW3,*pb3;
  const float *dW1,*db1,*dW2,*db2,*dW3,*db3,*dW4,*db4;
};

// LDS-resident dense stage with configurable LDS strides (bank-conflict padding).
// out[s][j] = act(sum_i in[s][i]*W[i][j] + b[j]); thread owns column jt=t%DOUT.
template<int DIN, int DOUT, int SIN, int SOUT, bool RELU, bool BIAS>
__device__ __forceinline__ void stage(const float* in_lds, float* out_lds,
                                      const float* __restrict__ W,
                                      const float* __restrict__ b, int t) {
  constexpr int NSG = 256 / DOUT;
  constexpr int NS  = STILE / NSG;
  const int jt = t % DOUT;
  const int sg = t / DOUT;
  float acc[NS];
#pragma unroll
  for (int k = 0; k < NS; ++k) acc[k] = BIAS ? b[jt] : 0.0f;
#pragma unroll 2
  for (int i = 0; i < DIN; ++i) {
    float w = W[i * DOUT + jt];
#pragma unroll
    for (int k = 0; k < NS; ++k)
      acc[k] = fmaf(in_lds[(sg * NS + k) * SIN + i], w, acc[k]);
  }
#pragma unroll
  for (int k = 0; k < NS; ++k) {
    float v = acc[k];
    if (RELU) v = fmaxf(v, 0.0f);
    out_lds[(sg * NS + k) * SOUT + jt] = v;
  }
}

// Full per-tile pipeline: computes alph[0..31], rgbl[0..31][3] for samples
// s0..s0+31 of a ray that HITS the box. Zeros for invalid samples.
// Ends with all writes visible (thread t's own alph[t]/rgbl via same thread,
// cross-thread via final __syncthreads).
__device__ __forceinline__ void process_tile(
    int t, int s0,
    float ox, float oy, float oz, float dx, float dy, float dz,
    float tmin, float nrm,
    const Wt& w, const float* __restrict__ grid,
    float* A, float* B, float (*ptl)[3], int* validl,
    float* alph, float (*rgbl)[3], const float* emb, int* anyvalid) {
  if (t == 0) *anyvalid = 0;
  __syncthreads();

  if (t < STILE) {
    int s = s0 + t;
    float px = 0.f, py = 0.f, pz = 0.f;
    int mv = 0;
    if (s < NSAMP) {
      float ix = tmin + (0.0078125f * (float)s) / nrm;  // STEPSIZE*VOXEL*s/|d|
      px = ox + dx * ix;
      py = oy + dy * ix;
      pz = oz + dz * ix;
      mv = !(px < -1.f || px > 1.f || py < -1.f || py > 1.f ||
             pz < -1.f || pz > 1.f);
    }
    ptl[t][0] = px; ptl[t][1] = py; ptl[t][2] = pz;
    validl[t] = mv;
    alph[t] = 0.0f;
    rgbl[t][0] = 0.0f; rgbl[t][1] = 0.0f; rgbl[t][2] = 0.0f;
    if (mv) *anyvalid = 1;
  }
  __syncthreads();
  if (!*anyvalid) return;

  // ---- trilinear interp: thread (s = t&31, c = t>>5), 4 channels ----
  if (t < 128) {
    int s = t & 31, c = t >> 5;
    float mpv = 0.0f;
    if (validl[s]) {
      float px = ptl[s][0], py = ptl[s][1], pz = ptl[s][2];
      float ixf = fminf(fmaxf((px + 1.0f) * 0.5f * 255.0f, 0.0f), 255.0f);
      float iyf = fminf(fmaxf((py + 1.0f) * 0.5f * 255.0f, 0.0f), 255.0f);
      float izf = fminf(fmaxf((pz + 1.0f) * 0.5f * 255.0f, 0.0f), 255.0f);
      int x0 = min((int)ixf, 254), y0 = min((int)iyf, 254), z0 = min((int)izf, 254);
      float fx = ixf - (float)x0, fy = iyf - (float)y0, fz = izf - (float)z0;
      const float* gc = grid + (size_t)c * 16777216u;
      int bx0 = x0 << 16, bx1 = bx0 + 65536;
      int by0 = y0 << 8,  by1 = by0 + 256;
      float c000 = gc[bx0+by0+z0], c001 = gc[bx0+by0+z0+1];
      float c010 = gc[bx0+by1+z0], c011 = gc[bx0+by1+z0+1];
      float c100 = gc[bx1+by0+z0], c101 = gc[bx1+by0+z0+1];
      float c110 = gc[bx1+by1+z0], c111 = gc[bx1+by1+z0+1];
      float c00 = c000*(1.f-fz) + c001*fz;
      float c01 = c010*(1.f-fz) + c011*fz;
      float c10 = c100*(1.f-fz) + c101*fz;
      float c11 = c110*(1.f-fz) + c111*fz;
      float c0 = c00*(1.f-fy) + c01*fy;
      float c1 = c10*(1.f-fy) + c11*fy;
      mpv = c0*(1.f-fx) + c1*fx;
    }
    A[s*5 + c] = mpv;     // stride 5: conflict-light
  }
  __syncthreads();

  stage<4,128,5,128,true,true>(A, B, w.mW1, w.mb1, t);    __syncthreads();
  stage<128,128,128,128,true,true>(B, A, w.mW2, w.mb2, t);__syncthreads();
  stage<128,32,128,33,false,true>(A, B, w.mW3, w.mb3, t); __syncthreads();

  // softmax over 32 logits, one thread per sample; stride-33 → conflict-free
  if (t < STILE) {
    float m = -1e30f;
    for (int i = 0; i < 32; ++i) m = fmaxf(m, B[t*33+i]);
    float sum = 0.0f;
    for (int i = 0; i < 32; ++i) { float e = expf(B[t*33+i] - m); B[t*33+i] = e; sum += e; }
    float inv = 1.0f / sum;
    for (int i = 0; i < 32; ++i) B[t*33+i] *= inv;
  }
  __syncthreads();

  stage<32,64,33,64,false,false>(B, A, w.fv, nullptr, t); __syncthreads();
  stage<64,64,64,64,true,true>(A, B, w.pW1, w.pb1, t);    __syncthreads();
  stage<64,64,64,64,true,true>(B, A, w.pW2, w.pb2, t);    __syncthreads();
  stage<64,16,64,17,false,true>(A, B, w.pW3, w.pb3, t);   __syncthreads();

  // alpha from pos[...,0]; build rgb_feat = [rgb_latent(15), emb(39)] in A (stride 55)
  if (t < STILE) {
    if (validl[t]) {
      float x = B[t*17] + ACT_SHIFT;
      float sp = fmaxf(x, 0.0f) + log1pf(expf(-fabsf(x)));  // stable softplus
      alph[t] = 1.0f - expf(-sp);
    }
  }
  for (int idx = t; idx < STILE*54; idx += 256) {
    int s = idx / 54, j = idx % 54;
    float val = (j < 15) ? (validl[s] ? B[s*17 + 1 + j] : 0.0f) : emb[j - 15];
    A[s*55 + j] = val;
  }
  __syncthreads();

  stage<54,64,55,64,true,true>(A, B, w.dW1, w.db1, t); __syncthreads();
  stage<64,64,64,64,true,true>(B, A, w.dW2, w.db2, t); __syncthreads();
  stage<64,64,64,65,true,true>(A, B, w.dW3, w.db3, t); __syncthreads();

  if (t < 96) {   // raw_rgb (dout=3) + sigmoid; B stride 65 → conflict-free reads
    int s = t / 3, c = t % 3;
    if (validl[s]) {
      float acc = w.db4[c];
      for (int i = 0; i < 64; ++i) acc = fmaf(B[s*65+i], w.dW4[i*3+c], acc);
      rgbl[s][c] = 1.0f / (1.0f + expf(-acc));
    }
  }
  __syncthreads();
}

// ---- ray setup shared by both kernels ----
__device__ __forceinline__ bool ray_setup(
    const float* rays_o, const float* rays_d, int r,
    float& ox, float& oy, float& oz, float& dx, float& dy, float& dz,
    float& tmin, float& nrm) {
  ox = rays_o[r*3+0]; oy = rays_o[r*3+1]; oz = rays_o[r*3+2];
  dx = rays_d[r*3+0]; dy = rays_d[r*3+1]; dz = rays_d[r*3+2];
  const float vx = (dx == 0.0f) ? 1e-6f : dx;
  const float vy = (dy == 0.0f) ? 1e-6f : dy;
  const float vz = (dz == 0.0f) ? 1e-6f : dz;
  const float rax = ( 1.0f - ox) / vx, rbx = (-1.0f - ox) / vx;
  const float ray_ = ( 1.0f - oy) / vy, rby = (-1.0f - oy) / vy;
  const float raz = ( 1.0f - oz) / vz, rbz = (-1.0f - oz) / vz;
  tmin = fmaxf(fmaxf(fminf(rax,rbx), fminf(ray_,rby)), fminf(raz,rbz));
  tmin = fminf(fmaxf(tmin, 0.2f), 3.0f);
  float tmax = fminf(fminf(fmaxf(rax,rbx), fmaxf(ray_,rby)), fmaxf(raz,rbz));
  tmax = fminf(fmaxf(tmax, 0.2f), 3.0f);
  nrm = sqrtf(dx*dx + dy*dy + dz*dz);
  return tmax <= tmin;  // true = miss
}

__device__ __forceinline__ void dir_embed(const float* viewdirs, int r, int t,
                                          float* emb) {
  if (t < 39) {
    const float v0 = viewdirs[r*3+0], v1 = viewdirs[r*3+1], v2 = viewdirs[r*3+2];
    float val;
    if (t < 3) {
      val = (t==0) ? v0 : ((t==1) ? v1 : v2);
    } else {
      int q = t - 3, fr = q / 6, rm = q % 6;
      float f = (float)(1 << fr);
      int c = rm % 3;
      float comp = (c==0) ? v0 : ((c==1) ? v1 : v2);
      float ang = comp * f;
      val = (rm < 3) ? sinf(ang) : cosf(ang);
    }
    emb[t] = val;
  }
}

// ============ kernel A: one block per (chunk, ray); writes (alpha,rgb) ============
extern "C" __global__ void __launch_bounds__(256)
ssg_chunks(const float* __restrict__ rays_o, const float* __restrict__ rays_d,
           const float* __restrict__ viewdirs, const float* __restrict__ grid,
           Wt w, float4* __restrict__ ws4) {
  const int chunk = blockIdx.x;
  const int r = blockIdx.y;
  const int t = threadIdx.x;

  __shared__ float A[STILE * 128];
  __shared__ float B[STILE * 128];
  __shared__ float ptl[STILE][3];
  __shared__ int   validl[STILE];
  __shared__ float alph[STILE];
  __shared__ float rgbl[STILE][3];
  __shared__ float emb[40];
  __shared__ int   anyvalid;

  float ox, oy, oz, dx, dy, dz, tmin, nrm;
  bool miss = ray_setup(rays_o, rays_d, r, ox, oy, oz, dx, dy, dz, tmin, nrm);

  if (miss) {
    if (t < STILE) ws4[(size_t)r * NSPAD + chunk * STILE + t] =
        make_float4(0.f, 0.f, 0.f, 0.f);
    return;
  }

  dir_embed(viewdirs, r, t, emb);

  process_tile(t, chunk * STILE, ox, oy, oz, dx, dy, dz, tmin, nrm,
               w, grid, A, B, ptl, validl, alph, rgbl, emb, &anyvalid);

  if (t < STILE)
    ws4[(size_t)r * NSPAD + chunk * STILE + t] =
        make_float4(alph[t], rgbl[t][0], rgbl[t][1], rgbl[t][2]);
}

// ============ kernel B: one wave per ray; prefix-product scan ============
extern "C" __global__ void __launch_bounds__(256)
ssg_scan(const float4* __restrict__ ws4, float* __restrict__ out, int n_rays) {
  const int wid = (blockIdx.x * 256 + threadIdx.x) >> 6;
  const int ln  = threadIdx.x & 63;
  if (wid >= n_rays) return;
  const float4* base = ws4 + (size_t)wid * NSPAD;

  float T = 1.0f, ar = 0.0f, ag = 0.0f, ab = 0.0f;
#pragma unroll
  for (int c = 0; c < NSPAD / 64; ++c) {
    float4 v = base[c * 64 + ln];
    float a = v.x;
    float q = fmaxf(1.0f - a, 1e-10f);
    float p = q;
#pragma unroll
    for (int off = 1; off < 64; off <<= 1) {
      float o = __shfl_up(p, off);
      if (ln >= off) p *= o;
    }
    float pe = __shfl_up(p, 1);
    if (ln == 0) pe = 1.0f;
    float wgt = a * T * pe;            // alpha * T_in * prod_{<ln}(1-a)
    ar = fmaf(wgt, v.y, ar);
    ag = fmaf(wgt, v.z, ag);
    ab = fmaf(wgt, v.w, ab);
    T *= __shfl(p, 63);
  }
#pragma unroll
  for (int off = 32; off; off >>= 1) {
    ar += __shfl_down(ar, off);
    ag += __shfl_down(ag, off);
    ab += __shfl_down(ab, off);
  }
  if (ln == 0) {
    out[wid*3+0] = ar + T;   // + alphainv_cum[-1] * BG, BG=1
    out[wid*3+1] = ag + T;
    out[wid*3+2] = ab + T;
  }
}

// ============ fallback: monolithic one-ray-per-block (small ws) ============
extern "C" __global__ void __launch_bounds__(256)
ssg_render(const float* __restrict__ rays_o, const float* __restrict__ rays_d,
           const float* __restrict__ viewdirs, const float* __restrict__ grid,
           Wt w, float* __restrict__ out) {
  const int r = blockIdx.x;
  const int t = threadIdx.x;

  __shared__ float A[STILE * 128];
  __shared__ float B[STILE * 128];
  __shared__ float ptl[STILE][3];
  __shared__ int   validl[STILE];
  __shared__ float alph[STILE];
  __shared__ float rgbl[STILE][3];
  __shared__ float emb[40];
  __shared__ int   anyvalid;

  float ox, oy, oz, dx, dy, dz, tmin, nrm;
  bool miss = ray_setup(rays_o, rays_d, r, ox, oy, oz, dx, dy, dz, tmin, nrm);
  if (miss) {
    if (t < 3) out[r*3+t] = 1.0f;
    return;
  }
  dir_embed(viewdirs, r, t, emb);

  float T = 1.0f, accr = 0.0f, accg = 0.0f, accb = 0.0f;
  for (int s0 = 0; s0 < NSAMP; s0 += STILE) {
    process_tile(t, s0, ox, oy, oz, dx, dy, dz, tmin, nrm,
                 w, grid, A, B, ptl, validl, alph, rgbl, emb, &anyvalid);
    if (t == 0) {
      int smax = min(STILE, NSAMP - s0);
      for (int k = 0; k < smax; ++k) {
        float a = alph[k];
        float wgt = a * T;
        accr = fmaf(wgt, rgbl[k][0], accr);
        accg = fmaf(wgt, rgbl[k][1], accg);
        accb = fmaf(wgt, rgbl[k][2], accb);
        T *= fmaxf(1.0f - a, 1e-10f);
      }
    }
    __syncthreads();
  }
  if (t == 0) {
    out[r*3+0] = accr + T;
    out[r*3+1] = accg + T;
    out[r*3+2] = accb + T;
  }
}

extern "C" void kernel_launch(void* const* d_in, const int* in_sizes, int n_in,
                              void* d_out, int out_size, void* d_ws, size_t ws_size,
                              hipStream_t stream) {
  Wt w;
  const float* rays_o   = (const float*)d_in[0];
  const float* rays_d   = (const float*)d_in[1];
  const float* viewdirs = (const float*)d_in[2];
  const float* grid     = (const float*)d_in[3];
  w.fv  = (const float*)d_in[4];
  w.mW1 = (const float*)d_in[5];  w.mb1 = (const float*)d_in[6];
  w.mW2 = (const float*)d_in[7];  w.mb2 = (const float*)d_in[8];
  w.mW3 = (const float*)d_in[9];  w.mb3 = (const float*)d_in[10];
  w.pW1 = (const float*)d_in[11]; w.pb1 = (const float*)d_in[12];
  w.pW2 = (const float*)d_in[13]; w.pb2 = (const float*)d_in[14];
  w.pW3 = (const float*)d_in[15]; w.pb3 = (const float*)d_in[16];
  w.dW1 = (const float*)d_in[17]; w.db1 = (const float*)d_in[18];
  w.dW2 = (const float*)d_in[19]; w.db2 = (const float*)d_in[20];
  w.dW3 = (const float*)d_in[21]; w.db3 = (const float*)d_in[22];
  w.dW4 = (const float*)d_in[23]; w.db4 = (const float*)d_in[24];
  float* out = (float*)d_out;

  const int n_rays = in_sizes[0] / 3;
  const size_t need = (size_t)n_rays * NSPAD * sizeof(float4);

  if (ws_size >= need) {
    dim3 grid_a(NCHUNK, n_rays);
    ssg_chunks<<<grid_a, 256, 0, stream>>>(rays_o, rays_d, viewdirs, grid, w,
                                           (float4*)d_ws);
    int nblk = (n_rays * 64 + 255) / 256;
    ssg_scan<<<nblk, 256, 0, stream>>>((const float4*)d_ws, out, n_rays);
  } else {
    ssg_render<<<n_rays, 256, 0, stream>>>(rays_o, rays_d, viewdirs, grid, w, out);
  }
}

// Round 3
// 144.300 us; speedup vs baseline: 7.2800x; 3.2514x over previous
//
#include <hip/hip_runtime.h>
#include <math.h>

#define ACT_SHIFT -4.5951198501345889f
#define SB 96                       // samples per MLP block
#define NSLOTMAX (4096*446)

typedef _Float16 f16;
typedef f16 f16x8 __attribute__((ext_vector_type(8)));
typedef f16 f16x2 __attribute__((ext_vector_type(2)));
typedef float f32x4 __attribute__((ext_vector_type(4)));

// ---- workspace layout (bytes) ----
#define OFF_CNT  0
#define OFF_RAYI 256                        // int4 * 4096
#define OFF_RAYF (OFF_RAYI + 4096*16)       // float2 * 4096 {tmin, nrm}
#define OFF_EMBW (OFF_RAYF + 4096*8)        // float * 4096*64
#define OFF_WTS  (OFF_EMBW + 4096*64*4)     // f16 * 47104
#define OFF_SLOT (OFF_WTS + 94208)          // int * NSLOTMAX
#define OFF_WS4H (OFF_SLOT + NSLOTMAX*4)    // ushort4 (f16 alpha,r,g,b) * NSLOTMAX

// weight slab offsets (f16 elements), layout Wt[dout][din_padded]
#define W_MW1 0       /* 128 x 32  */
#define W_MW2 4096    /* 128 x 128 */
#define W_MW3 20480   /* 32  x 128 */
#define W_FV  24576   /* 64  x 32  */
#define W_P1  26624   /* 64  x 64  */
#define W_P2  30720   /* 64  x 64  */
#define W_P3  34816   /* 16  x 64  */
#define W_D1  35840   /* 64  x 32  */
#define W_D2  37888   /* 64  x 64  */
#define W_D3  41984   /* 64  x 64  */
#define W_D4  46080   /* 16  x 64  */
#define W_TOT 47104

static __device__ __forceinline__ unsigned short f2h(float x) {
  f16 h = (f16)x; return *(unsigned short*)&h;
}
static __device__ __forceinline__ float h2f(unsigned short u) {
  return (float)(*(f16*)&u);
}

// identical math in setup & mlp kernels (validity must agree bit-exactly)
static __device__ __forceinline__ void sample_point(
    float ox, float oy, float oz, float dx, float dy, float dz,
    float tmin, float nrm, int s, float& px, float& py, float& pz) {
  float ix = tmin + (0.0078125f * (float)s) / nrm;
  px = ox + dx * ix; py = oy + dy * ix; pz = oz + dz * ix;
}
static __device__ __forceinline__ int in_box(float px, float py, float pz) {
  return !(px < -1.f || px > 1.f || py < -1.f || py > 1.f ||
           pz < -1.f || pz > 1.f);
}

static __device__ __forceinline__ bool ray_setup(
    const float* rays_o, const float* rays_d, int r,
    float& ox, float& oy, float& oz, float& dx, float& dy, float& dz,
    float& tmin, float& nrm) {
  ox = rays_o[r*3+0]; oy = rays_o[r*3+1]; oz = rays_o[r*3+2];
  dx = rays_d[r*3+0]; dy = rays_d[r*3+1]; dz = rays_d[r*3+2];
  const float vx = (dx == 0.0f) ? 1e-6f : dx;
  const float vy = (dy == 0.0f) ? 1e-6f : dy;
  const float vz = (dz == 0.0f) ? 1e-6f : dz;
  const float rax = ( 1.0f - ox) / vx, rbx = (-1.0f - ox) / vx;
  const float ray_ = ( 1.0f - oy) / vy, rby = (-1.0f - oy) / vy;
  const float raz = ( 1.0f - oz) / vz, rbz = (-1.0f - oz) / vz;
  tmin = fmaxf(fmaxf(fminf(rax,rbx), fminf(ray_,rby)), fminf(raz,rbz));
  tmin = fminf(fmaxf(tmin, 0.2f), 3.0f);
  float tmax = fminf(fminf(fmaxf(rax,rbx), fmaxf(ray_,rby)), fmaxf(raz,rbz));
  tmax = fminf(fmaxf(tmax, 0.2f), 3.0f);
  nrm = sqrtf(dx*dx + dy*dy + dz*dz);
  return tmax <= tmin;  // miss
}

// ============ kernel 1: per-ray valid range + packed slot map ============
extern "C" __global__ void __launch_bounds__(256)
k_setup(const float* __restrict__ rays_o, const float* __restrict__ rays_d,
        int* __restrict__ cnt, int4* __restrict__ rayi,
        float2* __restrict__ rayf, int* __restrict__ slot_map) {
  int r = blockIdx.x * 256 + threadIdx.x;
  if (r >= 4096) return;
  float ox,oy,oz,dx,dy,dz,tmin,nrm;
  bool miss = ray_setup(rays_o, rays_d, r, ox,oy,oz,dx,dy,dz, tmin, nrm);
  rayf[r] = make_float2(tmin, nrm);
  if (miss) { rayi[r] = make_int4(0,0,0,0); return; }
  int first = -1, last = -2;
  for (int s = 0; s < 446; ++s) {
    float px,py,pz;
    sample_point(ox,oy,oz,dx,dy,dz,tmin,nrm,s,px,py,pz);
    if (in_box(px,py,pz)) { if (first < 0) first = s; last = s; }
  }
  int n_s = (first >= 0) ? (last - first + 1) : 0;
  int base = 0;
  if (n_s > 0) base = atomicAdd(cnt, n_s);
  rayi[r] = make_int4(base, first, n_s, 0);
  for (int i = 0; i < n_s; ++i) slot_map[base + i] = (r << 9) | (first + i);
}

// ============ kernel 2: per-ray dir-embed folded into dW1 -> embW ============
extern "C" __global__ void __launch_bounds__(256)
k_embw(const float* __restrict__ viewdirs, const float* __restrict__ dW1,
       const float* __restrict__ db1, float* __restrict__ embW) {
  int idx = blockIdx.x * 256 + threadIdx.x;
  if (idx >= 4096*64) return;
  int ray = idx >> 6, o = idx & 63;
  float v0 = viewdirs[ray*3+0], v1 = viewdirs[ray*3+1], v2 = viewdirs[ray*3+2];
  float acc = db1[o];
  acc = fmaf(v0, dW1[15*64+o], acc);
  acc = fmaf(v1, dW1[16*64+o], acc);
  acc = fmaf(v2, dW1[17*64+o], acc);
#pragma unroll
  for (int fr = 0; fr < 6; ++fr) {
    float f = (float)(1 << fr);
    int rb = 18 + fr*6;
    acc = fmaf(sinf(v0*f), dW1[(rb+0)*64+o], acc);
    acc = fmaf(sinf(v1*f), dW1[(rb+1)*64+o], acc);
    acc = fmaf(sinf(v2*f), dW1[(rb+2)*64+o], acc);
    acc = fmaf(cosf(v0*f), dW1[(rb+3)*64+o], acc);
    acc = fmaf(cosf(v1*f), dW1[(rb+4)*64+o], acc);
    acc = fmaf(cosf(v2*f), dW1[(rb+5)*64+o], acc);
  }
  embW[idx] = acc;
}

// ============ kernel 3: transpose/pad all weights to f16 Wt[dout][din] ========
extern "C" __global__ void __launch_bounds__(256)
k_pack(const float* __restrict__ mW1, const float* __restrict__ mW2,
       const float* __restrict__ mW3, const float* __restrict__ fv,
       const float* __restrict__ pW1, const float* __restrict__ pW2,
       const float* __restrict__ pW3, const float* __restrict__ dW1,
       const float* __restrict__ dW2, const float* __restrict__ dW3,
       const float* __restrict__ dW4, f16* __restrict__ wts) {
  int i = blockIdx.x * 256 + threadIdx.x;
  if (i >= W_TOT) return;
  float v = 0.f; int l, o, k;
  if (i < W_MW2)        { l=i-W_MW1; o=l>>5; k=l&31;  if (k<4)  v = mW1[k*128+o]; }
  else if (i < W_MW3)   { l=i-W_MW2; o=l>>7; k=l&127; v = mW2[k*128+o]; }
  else if (i < W_FV)    { l=i-W_MW3; o=l>>7; k=l&127; v = mW3[k*32+o]; }
  else if (i < W_P1)    { l=i-W_FV;  o=l>>5; k=l&31;  v = fv[k*64+o]; }
  else if (i < W_P2)    { l=i-W_P1;  o=l>>6; k=l&63;  v = pW1[k*64+o]; }
  else if (i < W_P3)    { l=i-W_P2;  o=l>>6; k=l&63;  v = pW2[k*64+o]; }
  else if (i < W_D1)    { l=i-W_P3;  o=l>>6; k=l&63;  v = pW3[k*16+o]; }
  else if (i < W_D2)    { l=i-W_D1;  o=l>>5; k=l&31;  if (k<15) v = dW1[k*64+o]; }
  else if (i < W_D3)    { l=i-W_D2;  o=l>>6; k=l&63;  v = dW2[k*64+o]; }
  else if (i < W_D4)    { l=i-W_D3;  o=l>>6; k=l&63;  v = dW3[k*64+o]; }
  else                  { l=i-W_D4;  o=l>>6; k=l&63;  if (o<3)  v = dW4[k*3+o]; }
  wts[i] = (f16)v;
}

// ---- generic MFMA layer over SB=96 samples, 4 waves split output tiles ----
// BMODE: 0 none, 1 colwise f32 bias, 2 per-ray embW bias, 3 pos-head, 4 rgb-head
template<int KP, int NP, bool RELU, int BMODE>
__device__ __forceinline__ void layer_mm(
    const f16* __restrict__ Wt, const float* __restrict__ bias,
    const float* __restrict__ embW, const int* sinfo,
    const f16* inb, f16* outb, int wave, int lane,
    int blockbase, unsigned short* ws4h) {
  constexpr int MB = SB/16, NB = NP/16, NT = MB*NB, TPW = (NT+3)/4, KS = KP/32;
  const int c = lane & 15, g = lane >> 4;
  f16x8 Bf[KS];
  int prev_nb = -1;
  for (int ti = 0; ti < TPW; ++ti) {
    int t = wave * TPW + ti;
    if (t >= NT) break;
    int nb = t / MB, mb = t % MB;
    if (nb != prev_nb) {
      prev_nb = nb;
      const f16* wp = Wt + (size_t)(nb*16 + c) * KP + g*8;
#pragma unroll
      for (int ks = 0; ks < KS; ++ks)
        Bf[ks] = *(const f16x8*)(wp + ks*32);
    }
    f32x4 acc = {0.f, 0.f, 0.f, 0.f};
#pragma unroll
    for (int ks = 0; ks < KS; ++ks) {
      int row = mb*16 + c;
      int off = (row*256 + (ks*32 + g*8)*2) ^ ((row & 7) << 4);
      f16x8 Af = *(const f16x8*)((const char*)inb + off);
      acc = __builtin_amdgcn_mfma_f32_16x16x32_f16(Af, Bf[ks], acc, 0, 0, 0);
    }
    int cc = nb*16 + c;
    float bv = 0.f;
    if (BMODE == 1 || BMODE == 3 || BMODE == 4) bv = bias[cc];
#pragma unroll
    for (int r = 0; r < 4; ++r) {
      int row = mb*16 + g*4 + r;
      float bb = bv;
      if (BMODE == 2) {
        int pk = sinfo[row];
        int ry = (pk < 0) ? 0 : (pk >> 1);
        bb = embW[ry*64 + cc];
      }
      float v = acc[r] + bb;
      if (BMODE <= 2) {
        if (RELU) v = fmaxf(v, 0.f);
        int off = (row*256 + cc*2) ^ ((row & 7) << 4);
        *(f16*)((char*)outb + off) = (f16)v;
      } else if (BMODE == 3) {          // pos head: alpha (cc==0) + rgb_latent
        int pk = sinfo[row];
        if (cc == 0) {
          if (pk >= 0) {
            float a = 0.f;
            if (pk & 1) {
              float x = v + ACT_SHIFT;
              float sp = fmaxf(x, 0.f) + log1pf(expf(-fabsf(x)));
              a = 1.f - expf(-sp);
            }
            ws4h[(size_t)(blockbase + row)*4 + 0] = f2h(a);
          }
        } else {
          int off = (row*256 + (cc-1)*2) ^ ((row & 7) << 4);
          *(f16*)((char*)outb + off) = (f16)v;
        }
      } else {                          // BMODE 4: rgb head
        int pk = sinfo[row];
        if (pk >= 0 && cc < 3) {
          float rv = (pk & 1) ? (1.f / (1.f + expf(-v))) : 0.f;
          ws4h[(size_t)(blockbase + row)*4 + 1 + cc] = f2h(rv);
        }
      }
    }
  }
}

// ============ kernel 4: packed-sample MFMA MLP pipeline ============
extern "C" __global__ void __launch_bounds__(256)
k_mlp(const float* __restrict__ rays_o, const float* __restrict__ rays_d,
      const float* __restrict__ grid, const int* __restrict__ slot_map,
      const float2* __restrict__ rayf, const float* __restrict__ embW,
      const f16* __restrict__ wts, const int* __restrict__ cnt,
      const float* __restrict__ mb1, const float* __restrict__ mb2,
      const float* __restrict__ mb3, const float* __restrict__ pb1,
      const float* __restrict__ pb2, const float* __restrict__ pb3,
      const float* __restrict__ db2, const float* __restrict__ db3,
      const float* __restrict__ db4, unsigned short* __restrict__ ws4h) {
  const int total = *cnt;
  const int blockbase = blockIdx.x * SB;
  if (blockbase >= total) return;
  const int tid = threadIdx.x;
  const int wave = tid >> 6, lane = tid & 63;

  __shared__ __align__(16) f16 X[SB*128];
  __shared__ __align__(16) f16 Y[SB*128];
  __shared__ int sinfo[SB];       // ray*2|valid, or -2 if slot >= total

  // zero pad dims 4..31 of X (first layer reads KP=32)
  for (int idx = tid; idx < SB*14; idx += 256) {
    int row = idx / 14, dim = 4 + (idx % 14)*2;
    int off = (row*256 + dim*2) ^ ((row & 7) << 4);
    f16x2 z = {(f16)0.f, (f16)0.f};
    *(f16x2*)((char*)X + off) = z;
  }

  // trilinear interp: 2 threads per sample, 2 channels each
  if (tid < SB*2) {
    int sl = tid >> 1, c0 = (tid & 1) * 2;
    int slot = blockbase + sl;
    int pk = -2;
    float ch0 = 0.f, ch1 = 0.f;
    if (slot < total) {
      int mi = slot_map[slot];
      int ray = mi >> 9, s = mi & 511;
      float2 tf = rayf[ray];
      float ox = rays_o[ray*3+0], oy = rays_o[ray*3+1], oz = rays_o[ray*3+2];
      float dx = rays_d[ray*3+0], dy = rays_d[ray*3+1], dz = rays_d[ray*3+2];
      float px, py, pz;
      sample_point(ox,oy,oz,dx,dy,dz, tf.x, tf.y, s, px,py,pz);
      pk = ray*2 + in_box(px,py,pz);
      float ixf = fminf(fmaxf((px + 1.f) * 0.5f * 255.f, 0.f), 255.f);
      float iyf = fminf(fmaxf((py + 1.f) * 0.5f * 255.f, 0.f), 255.f);
      float izf = fminf(fmaxf((pz + 1.f) * 0.5f * 255.f, 0.f), 255.f);
      int x0 = min((int)ixf, 254), y0 = min((int)iyf, 254), z0 = min((int)izf, 254);
      float fx = ixf - (float)x0, fy = iyf - (float)y0, fz = izf - (float)z0;
      int bx0 = x0 << 16, bx1 = bx0 + 65536;
      int by0 = y0 << 8,  by1 = by0 + 256;
#pragma unroll
      for (int q = 0; q < 2; ++q) {
        const float* gc = grid + (size_t)(c0 + q) * 16777216u;
        float c000 = gc[bx0+by0+z0], c001 = gc[bx0+by0+z0+1];
        float c010 = gc[bx0+by1+z0], c011 = gc[bx0+by1+z0+1];
        float c100 = gc[bx1+by0+z0], c101 = gc[bx1+by0+z0+1];
        float c110 = gc[bx1+by1+z0], c111 = gc[bx1+by1+z0+1];
        float c00 = c000*(1.f-fz) + c001*fz;
        float c01 = c010*(1.f-fz) + c011*fz;
        float c10 = c100*(1.f-fz) + c101*fz;
        float c11 = c110*(1.f-fz) + c111*fz;
        float c0v = c00*(1.f-fy) + c01*fy;
        float c1v = c10*(1.f-fy) + c11*fy;
        float mv = c0v*(1.f-fx) + c1v*fx;
        if (q == 0) ch0 = mv; else ch1 = mv;
      }
    }
    if ((tid & 1) == 0) sinfo[sl] = pk;
    int off = (sl*256 + c0*2) ^ ((sl & 7) << 4);
    f16x2 w2 = {(f16)ch0, (f16)ch1};
    *(f16x2*)((char*)X + off) = w2;
  }
  __syncthreads();

  layer_mm<32,128,true,1>(wts+W_MW1, mb1, nullptr, sinfo, X, Y, wave, lane, blockbase, ws4h);
  __syncthreads();
  layer_mm<128,128,true,1>(wts+W_MW2, mb2, nullptr, sinfo, Y, X, wave, lane, blockbase, ws4h);
  __syncthreads();
  layer_mm<128,32,false,1>(wts+W_MW3, mb3, nullptr, sinfo, X, Y, wave, lane, blockbase, ws4h);
  __syncthreads();

  // softmax over 32 logits, thread per sample
  if (tid < SB) {
    int row = tid;
    float v[32];
#pragma unroll
    for (int p = 0; p < 16; ++p) {
      int off = (row*256 + p*4) ^ ((row & 7) << 4);
      f16x2 two = *(const f16x2*)((const char*)Y + off);
      v[2*p] = (float)two[0]; v[2*p+1] = (float)two[1];
    }
    float m = -1e30f;
#pragma unroll
    for (int i = 0; i < 32; ++i) m = fmaxf(m, v[i]);
    float sum = 0.f;
#pragma unroll
    for (int i = 0; i < 32; ++i) { v[i] = expf(v[i] - m); sum += v[i]; }
    float inv = 1.f / sum;
#pragma unroll
    for (int p = 0; p < 16; ++p) {
      int off = (row*256 + p*4) ^ ((row & 7) << 4);
      f16x2 two = {(f16)(v[2*p]*inv), (f16)(v[2*p+1]*inv)};
      *(f16x2*)((char*)Y + off) = two;
    }
  }
  __syncthreads();

  layer_mm<32,64,false,0>(wts+W_FV, nullptr, nullptr, sinfo, Y, X, wave, lane, blockbase, ws4h);
  __syncthreads();
  layer_mm<64,64,true,1>(wts+W_P1, pb1, nullptr, sinfo, X, Y, wave, lane, blockbase, ws4h);
  __syncthreads();
  layer_mm<64,64,true,1>(wts+W_P2, pb2, nullptr, sinfo, Y, X, wave, lane, blockbase, ws4h);
  __syncthreads();
  layer_mm<64,16,false,3>(wts+W_P3, pb3, nullptr, sinfo, X, Y, wave, lane, blockbase, ws4h);
  __syncthreads();
  layer_mm<32,64,true,2>(wts+W_D1, nullptr, embW, sinfo, Y, X, wave, lane, blockbase, ws4h);
  __syncthreads();
  layer_mm<64,64,true,1>(wts+W_D2, db2, nullptr, sinfo, X, Y, wave, lane, blockbase, ws4h);
  __syncthreads();
  layer_mm<64,64,true,1>(wts+W_D3, db3, nullptr, sinfo, Y, X, wave, lane, blockbase, ws4h);
  __syncthreads();
  layer_mm<64,16,false,4>(wts+W_D4, db4, nullptr, sinfo, X, Y, wave, lane, blockbase, ws4h);
}

// ============ kernel 5: per-ray transmittance scan over packed slots ==========
extern "C" __global__ void __launch_bounds__(256)
k_scan(const ushort4* __restrict__ ws4h, const int4* __restrict__ rayi,
       float* __restrict__ out) {
  const int wid = (blockIdx.x * 256 + threadIdx.x) >> 6;
  const int ln  = threadIdx.x & 63;
  if (wid >= 4096) return;
  int4 ri = rayi[wid];
  int base = ri.x, n_s = ri.z;

  float T = 1.0f, ar = 0.f, ag = 0.f, ab = 0.f;
  int nc = (n_s + 63) >> 6;
  for (int cck = 0; cck < nc; ++cck) {
    int j = cck*64 + ln;
    float a = 0.f, rr = 0.f, gg = 0.f, bb = 0.f;
    if (j < n_s) {
      ushort4 u = ws4h[(size_t)base + j];
      a = h2f(u.x); rr = h2f(u.y); gg = h2f(u.z); bb = h2f(u.w);
    }
    float p = fmaxf(1.0f - a, 1e-10f);
#pragma unroll
    for (int off = 1; off < 64; off <<= 1) {
      float o = __shfl_up(p, off);
      if (ln >= off) p *= o;
    }
    float pe = __shfl_up(p, 1);
    if (ln == 0) pe = 1.0f;
    float wgt = a * T * pe;
    ar = fmaf(wgt, rr, ar);
    ag = fmaf(wgt, gg, ag);
    ab = fmaf(wgt, bb, ab);
    T *= __shfl(p, 63);
  }
#pragma unroll
  for (int off = 32; off; off >>= 1) {
    ar += __shfl_down(ar, off);
    ag += __shfl_down(ag, off);
    ab += __shfl_down(ab, off);
  }
  if (ln == 0) {
    out[wid*3+0] = ar + T;
    out[wid*3+1] = ag + T;
    out[wid*3+2] = ab + T;
  }
}

extern "C" void kernel_launch(void* const* d_in, const int* in_sizes, int n_in,
                              void* d_out, int out_size, void* d_ws, size_t ws_size,
                              hipStream_t stream) {
  const float* rays_o   = (const float*)d_in[0];
  const float* rays_d   = (const float*)d_in[1];
  const float* viewdirs = (const float*)d_in[2];
  const float* grid     = (const float*)d_in[3];
  const float* fv       = (const float*)d_in[4];
  const float* mW1 = (const float*)d_in[5];  const float* mb1 = (const float*)d_in[6];
  const float* mW2 = (const float*)d_in[7];  const float* mb2 = (const float*)d_in[8];
  const float* mW3 = (const float*)d_in[9];  const float* mb3 = (const float*)d_in[10];
  const float* pW1 = (const float*)d_in[11]; const float* pb1 = (const float*)d_in[12];
  const float* pW2 = (const float*)d_in[13]; const float* pb2 = (const float*)d_in[14];
  const float* pW3 = (const float*)d_in[15]; const float* pb3 = (const float*)d_in[16];
  const float* dW1 = (const float*)d_in[17]; const float* db1 = (const float*)d_in[18];
  const float* dW2 = (const float*)d_in[19]; const float* db2 = (const float*)d_in[20];
  const float* dW3 = (const float*)d_in[21]; const float* db3 = (const float*)d_in[22];
  const float* dW4 = (const float*)d_in[23]; const float* db4 = (const float*)d_in[24];
  float* out = (float*)d_out;

  char* ws = (char*)d_ws;
  int*     cnt      = (int*)(ws + OFF_CNT);
  int4*    rayi     = (int4*)(ws + OFF_RAYI);
  float2*  rayf     = (float2*)(ws + OFF_RAYF);
  float*   embW     = (float*)(ws + OFF_EMBW);
  f16*     wts      = (f16*)(ws + OFF_WTS);
  int*     slot_map = (int*)(ws + OFF_SLOT);
  unsigned short* ws4h = (unsigned short*)(ws + OFF_WS4H);

  hipMemsetAsync(cnt, 0, 4, stream);
  k_setup<<<16, 256, 0, stream>>>(rays_o, rays_d, cnt, rayi, rayf, slot_map);
  k_embw<<<1024, 256, 0, stream>>>(viewdirs, dW1, db1, embW);
  k_pack<<<(W_TOT+255)/256, 256, 0, stream>>>(mW1, mW2, mW3, fv, pW1, pW2, pW3,
                                              dW1, dW2, dW3, dW4, wts);
  int nblk = (NSLOTMAX + SB - 1) / SB;
  k_mlp<<<nblk, 256, 0, stream>>>(rays_o, rays_d, grid, slot_map, rayf, embW,
                                  wts, cnt, mb1, mb2, mb3, pb1, pb2, pb3,
                                  db2, db3, db4, ws4h);
  k_scan<<<1024, 256, 0, stream>>>((const ushort4*)ws4h, rayi, out);
}